// Round 4
// baseline (24.509 us; speedup 1.0000x reference)
//
#include <hip/hip_runtime.h>

// Problem constants (from reference setup_inputs)
#define BB 4
#define LL 8192
#define DD 1024
#define MAXC (LL / 4)   // 2048

typedef float f32x4 __attribute__((ext_vector_type(4)));
typedef int   i32x4 __attribute__((ext_vector_type(4)));

// ---------------------------------------------------------------------------
// Single fused kernel: 2048 blocks x 256 threads, 4 output rows per block.
//
// Phase 1 (redundant per block, mask is L2-resident at 128 KB total):
//   thread t packs mask[b][t*32 .. t*32+31] into a 32-bit bitmask,
//   popc + wave shuffle-scan + 4-wave LDS round -> exclusive boundary
//   prefix P_t and per-batch total.
// Phase 2: for each of the block's 4 ranks r, the unique owning thread
//   walks its bitmask to find the source token position (boundary rank r
//   if r < total, else non-boundary rank r-total — matches
//   argsort(i + (~mask)*L)[:MAXC] exactly since all keys are distinct).
//   Writes take_idx / pad_mask for its rows.
// Phase 3: copy 4 x 4 KB rows (float4 nontemporal, fully coalesced),
//   zeros for ranks >= num_chunks.
//
// No inter-kernel dependency, no grid sync, no workspace.
// ---------------------------------------------------------------------------
__global__ __launch_bounds__(256, 8) void chunk_fused_kernel(
    const float* __restrict__ hs,       // [BB][LL][DD]
    const int*   __restrict__ mask,     // [BB][LL] 0/1
    float*       __restrict__ out_chunk,// [BB][MAXC][DD]
    float*       __restrict__ out_pad,  // [BB][MAXC]
    float*       __restrict__ out_tk)   // [BB][MAXC]
{
    const int t   = threadIdx.x;
    const int blk = blockIdx.x;            // 0..2047
    const int b   = blk >> 9;              // 512 blocks per batch
    const int r0  = (blk & 511) * 4;       // base output rank in batch

    // ---- phase 1: pack bits + scan ----
    const int* m = mask + (size_t)b * LL;
    const i32x4* m4 = reinterpret_cast<const i32x4*>(m + t * 32);
    unsigned int bits = 0;
#pragma unroll
    for (int j = 0; j < 8; ++j) {
        i32x4 v = m4[j];
        bits |= (unsigned int)(v.x & 1) << (4 * j + 0);
        bits |= (unsigned int)(v.y & 1) << (4 * j + 1);
        bits |= (unsigned int)(v.z & 1) << (4 * j + 2);
        bits |= (unsigned int)(v.w & 1) << (4 * j + 3);
    }
    const int s = __popc(bits);

    const int lane = t & 63;
    const int wid  = t >> 6;               // 4 waves
    int inc = s;
#pragma unroll
    for (int off = 1; off < 64; off <<= 1) {
        int n = __shfl_up(inc, off, 64);
        if (lane >= off) inc += n;
    }

    __shared__ int wsum[4];
    __shared__ int pos[4];
    if (lane == 63) wsum[wid] = inc;
    __syncthreads();

    int total = 0, wpre = 0;
#pragma unroll
    for (int w = 0; w < 4; ++w) {
        int x = wsum[w];
        total += x;
        wpre += (w < wid) ? x : 0;
    }
    const int P    = wpre + inc - s;       // boundaries before token t*32
    const int nbP  = t * 32 - P;           // non-boundaries before token t*32
    const int nc   = (total < MAXC) ? total : MAXC;

    // ---- phase 2: locate the 4 source positions ----
#pragma unroll
    for (int k = 0; k < 4; ++k) {
        const int rr = r0 + k;
        if (rr < total) {                  // boundary-sourced (uniform branch)
            if (rr >= P && rr < P + s) {
                unsigned int v = bits;
                for (int z = rr - P; z > 0; --z) v &= v - 1;
                pos[k] = t * 32 + __ffs(v) - 1;
            }
        } else {                           // non-boundary-sourced
            const int nr = rr - total;
            const int ns = 32 - s;
            if (nr >= nbP && nr < nbP + ns) {
                unsigned int v = ~bits;
                for (int z = nr - nbP; z > 0; --z) v &= v - 1;
                pos[k] = t * 32 + __ffs(v) - 1;
            }
        }
    }
    __syncthreads();

    if (t < 4) {
        const int rr = r0 + t;
        const int o  = b * MAXC + rr;
        out_tk[o]  = (float)pos[t];        // exact: < 2^24
        out_pad[o] = (rr < nc) ? 1.0f : 0.0f;
    }

    // ---- phase 3: copy rows ----
    f32x4 vals[4];
#pragma unroll
    for (int k = 0; k < 4; ++k) {
        const int rr = r0 + k;
        if (rr < nc) {
            const f32x4* src = reinterpret_cast<const f32x4*>(
                hs + ((size_t)b * LL + pos[k]) * DD);
            vals[k] = __builtin_nontemporal_load(&src[t]);
        } else {
            vals[k] = (f32x4){0.f, 0.f, 0.f, 0.f};
        }
    }

    f32x4* o = reinterpret_cast<f32x4*>(out_chunk + ((size_t)b * MAXC + r0) * DD);
#pragma unroll
    for (int k = 0; k < 4; ++k) {
        __builtin_nontemporal_store(vals[k], &o[k * 256 + t]);
    }
}

extern "C" void kernel_launch(void* const* d_in, const int* in_sizes, int n_in,
                              void* d_out, int out_size, void* d_ws, size_t ws_size,
                              hipStream_t stream) {
    const float* hs   = (const float*)d_in[0];   // [4][8192][1024] f32
    const int*   mask = (const int*)d_in[1];     // [4][8192] int (bool 0/1)

    float* out = (float*)d_out;
    float* out_chunk = out;                          // [4][2048][1024]
    float* out_pad   = out + (size_t)BB * MAXC * DD; // [4][2048]
    float* out_tk    = out_pad + (size_t)BB * MAXC;  // [4][2048]

    chunk_fused_kernel<<<BB * MAXC / 4, 256, 0, stream>>>(hs, mask, out_chunk,
                                                          out_pad, out_tk);
}

// Round 5
// 18.504 us; speedup vs baseline: 1.3245x; 1.3245x over previous
//
#include <hip/hip_runtime.h>

// Problem constants (from reference setup_inputs)
#define BB 4
#define LL 8192
#define DD 1024
#define MAXC (LL / 4)   // 2048

typedef float f32x4 __attribute__((ext_vector_type(4)));
typedef int   i32x4 __attribute__((ext_vector_type(4)));

// ---------------------------------------------------------------------------
// Kernel 1: per-batch boundary scan -> ranks -> take_idx / pad_mask.
// One block of 1024 threads per batch, 8 mask elements per thread.
// Wave-level shuffle scan + single LDS round for 16 wave sums.
// Semantics replicate: argsort(i + (~mask)*L)[:MAXC]
//   = boundary positions in index order, then non-boundary positions in
//     index order (all token_idx values distinct, so order is exact).
// ---------------------------------------------------------------------------
__global__ __launch_bounds__(1024) void chunk_scan_kernel(
    const int* __restrict__ mask,     // [BB][LL] 0/1
    int*       __restrict__ tk_int,   // ws: [BB][MAXC]
    int*       __restrict__ nchunks,  // ws: [BB]
    float*     __restrict__ out_pad,  // [BB][MAXC]
    float*     __restrict__ out_tk)   // [BB][MAXC]
{
    const int b = blockIdx.x;
    const int t = threadIdx.x;
    constexpr int PER = LL / 1024;    // 8

    const int* m = mask + (size_t)b * LL;
    const i32x4* m4 = reinterpret_cast<const i32x4*>(m + t * PER);
    i32x4 v0 = m4[0];
    i32x4 v1 = m4[1];
    int local[PER] = {v0.x, v0.y, v0.z, v0.w, v1.x, v1.y, v1.z, v1.w};

    int s = 0;
#pragma unroll
    for (int j = 0; j < PER; ++j) s += local[j];

    // Wave-level inclusive scan of per-thread sums (wave = 64 lanes).
    const int lane = t & 63;
    const int wid  = t >> 6;          // 16 waves
    int inc = s;
#pragma unroll
    for (int off = 1; off < 64; off <<= 1) {
        int n = __shfl_up(inc, off, 64);
        if (lane >= off) inc += n;
    }

    __shared__ int wsum[16];
    if (lane == 63) wsum[wid] = inc;
    __syncthreads();

    int wpre = 0, total = 0;
#pragma unroll
    for (int w = 0; w < 16; ++w) {    // broadcast reads, no conflicts
        int x = wsum[w];
        total += x;
        wpre += (w < wid) ? x : 0;
    }
    const int excl = wpre + inc - s;              // exclusive prefix (block)
    const int nc   = (total < MAXC) ? total : MAXC;

    // Assign each position its sorted rank and scatter.
    int pb = excl;                    // #boundary strictly before i
    const int base = t * PER;
#pragma unroll
    for (int j = 0; j < PER; ++j) {
        const int i = base + j;
        const int r = local[j] ? pb : (total + (i - pb));
        pb += local[j];
        if (r < MAXC) {
            const int o = b * MAXC + r;
            tk_int[o]  = i;
            out_tk[o]  = (float)i;    // exact: i < 2^24
            out_pad[o] = (r < nc) ? 1.0f : 0.0f;
        }
    }
    if (t == 0) nchunks[b] = nc;
}

// ---------------------------------------------------------------------------
// Kernel 2: gather rows. 2048 blocks x 256 threads; each block copies FOUR
// consecutive output rows (4 x 4 KB). Loads are CACHED (read set ~32 MB is
// L3-resident across replays); stores are nontemporal (write-once stream,
// don't evict the read set).
// ---------------------------------------------------------------------------
__global__ __launch_bounds__(256) void chunk_gather_kernel(
    const float* __restrict__ hs,       // [BB][LL][DD]
    const int*   __restrict__ tk_int,   // [BB][MAXC]
    const int*   __restrict__ nchunks,  // [BB]
    float*       __restrict__ out)      // [BB][MAXC][DD]
{
    const int t    = threadIdx.x;
    const int row0 = blockIdx.x * 4;    // 4 rows per block, same batch
    const int b    = row0 >> 11;        // / MAXC (2048)
    const int nc   = nchunks[b];

    f32x4 vals[4];
#pragma unroll
    for (int k = 0; k < 4; ++k) {
        const int row = row0 + k;
        const int r   = row & (MAXC - 1);
        if (r < nc) {
            const int i = tk_int[row];
            const f32x4* src =
                reinterpret_cast<const f32x4*>(hs + ((size_t)b * LL + i) * DD);
            vals[k] = src[t];                       // cached load (L3 hit on replays)
        } else {
            vals[k] = (f32x4){0.f, 0.f, 0.f, 0.f};
        }
    }

    f32x4* o = reinterpret_cast<f32x4*>(out + (size_t)row0 * DD);
#pragma unroll
    for (int k = 0; k < 4; ++k) {
        __builtin_nontemporal_store(vals[k], &o[k * 256 + t]);
    }
}

extern "C" void kernel_launch(void* const* d_in, const int* in_sizes, int n_in,
                              void* d_out, int out_size, void* d_ws, size_t ws_size,
                              hipStream_t stream) {
    const float* hs   = (const float*)d_in[0];   // [4][8192][1024] f32
    const int*   mask = (const int*)d_in[1];     // [4][8192] int (bool 0/1)

    float* out = (float*)d_out;
    float* out_chunk = out;                          // [4][2048][1024]
    float* out_pad   = out + (size_t)BB * MAXC * DD; // [4][2048]
    float* out_tk    = out_pad + (size_t)BB * MAXC;  // [4][2048]

    int* tk_int  = (int*)d_ws;                       // [4][2048]
    int* nchunks = tk_int + BB * MAXC;               // [4]

    chunk_scan_kernel<<<BB, 1024, 0, stream>>>(mask, tk_int, nchunks,
                                               out_pad, out_tk);
    chunk_gather_kernel<<<BB * MAXC / 4, 256, 0, stream>>>(hs, tk_int, nchunks,
                                                           out_chunk);
}